// Round 1
// baseline (14044.196 us; speedup 1.0000x reference)
//
#include <hip/hip_runtime.h>
#include <math.h>

typedef unsigned short u16;
typedef unsigned int   u32;

#define DEVI static __device__ __forceinline__

DEVI float bf2f(u16 u){ u32 x = ((u32)u) << 16; float f; __builtin_memcpy(&f, &x, 4); return f; }
DEVI u16 f2bf(float f){ u32 x; __builtin_memcpy(&x, &f, 4); u32 r = (x + 0x7fffu + ((x >> 16) & 1u)) >> 16; return (u16)r; }
DEVI float sigm(float x){ return 1.f / (1.f + __expf(-x)); }
DEVI float tanh_f(float x){ float e = __expf(2.f * x); return 1.f - 2.f / (e + 1.f); }

DEVI float blk_max(float v, float* sm){
#pragma unroll
  for (int m = 32; m; m >>= 1) v = fmaxf(v, __shfl_xor(v, m));
  __syncthreads();
  if ((threadIdx.x & 63) == 0) sm[threadIdx.x >> 6] = v;
  __syncthreads();
  return fmaxf(fmaxf(sm[0], sm[1]), fmaxf(sm[2], sm[3]));
}
DEVI float blk_sum(float v, float* sm){
#pragma unroll
  for (int m = 32; m; m >>= 1) v += __shfl_xor(v, m);
  __syncthreads();
  if ((threadIdx.x & 63) == 0) sm[threadIdx.x >> 6] = v;
  __syncthreads();
  return sm[0] + sm[1] + sm[2] + sm[3];
}

// ---------------- pack kernels ----------------
// Whh -> bf16 gate-interleaved: [d][k][j] = {W[k][j], W[k][256+j], W[k][512+j], W[k][768+j]}
__global__ void k_pack_whh(const float* __restrict__ Wf, const float* __restrict__ Wb, ushort4* __restrict__ out){
  int idx = blockIdx.x * 256 + threadIdx.x;      // 2*256*256
  int d = idx >> 16, k = (idx >> 8) & 255, j = idx & 255;
  const float* W = d ? Wb : Wf;
  ushort4 r;
  r.x = f2bf(W[k*1024 + j]);       r.y = f2bf(W[k*1024 + 256 + j]);
  r.z = f2bf(W[k*1024 + 512 + j]); r.w = f2bf(W[k*1024 + 768 + j]);
  out[idx] = r;
}

// dec weights rows: k<512 -> Wih row 128+k (ctx part); else Whh row k-512. layout [k][j] gate-interleaved
__global__ void k_pack_decw(const float* __restrict__ Wih, const float* __restrict__ Whh, ushort4* __restrict__ out){
  int idx = blockIdx.x * 256 + threadIdx.x;      // 768*256
  int k = idx >> 8, j = idx & 255;
  const float* row = (k < 512) ? (Wih + (size_t)(128 + k) * 1024) : (Whh + (size_t)(k - 512) * 1024);
  ushort4 r;
  r.x = f2bf(row[j]);       r.y = f2bf(row[256 + j]);
  r.z = f2bf(row[512 + j]); r.w = f2bf(row[768 + j]);
  out[idx] = r;
}

// ---------------- encoder ----------------
// xw[d][s][b][j] = gate-interleaved bf16 of emb@Wih + bias
__global__ void k_enc_pre(const int* __restrict__ src, const float* __restrict__ emb,
                          const float* __restrict__ Wf, const float* __restrict__ bf_,
                          const float* __restrict__ Wb, const float* __restrict__ bb_,
                          ushort4* __restrict__ xw){
  int blk = blockIdx.x;                 // ((d*400+s)*16+b)
  int j = threadIdx.x;
  int b = blk & 15; int rest = blk >> 4; int s = rest % 400; int d = rest / 400;
  const float* Wih = d ? Wb : Wf; const float* bias = d ? bb_ : bf_;
  int id = src[b * 400 + s];
  const float* er = emb + (size_t)id * 128;
  float a0 = bias[j], a1 = bias[256 + j], a2 = bias[512 + j], a3 = bias[768 + j];
  for (int e = 0; e < 128; ++e){
    float x = er[e];
    const float* wr = Wih + (size_t)e * 1024;
    a0 += x * wr[j]; a1 += x * wr[256 + j]; a2 += x * wr[512 + j]; a3 += x * wr[768 + j];
  }
  ushort4 r; r.x = f2bf(a0); r.y = f2bf(a1); r.z = f2bf(a2); r.w = f2bf(a3);
  xw[(size_t)blk * 256 + j] = r;
}

__global__ __launch_bounds__(256) void k_enc_lstm(const ushort4* __restrict__ xw, const ushort4* __restrict__ whh,
                                                  u16* __restrict__ enc_out, float* __restrict__ hfin, float* __restrict__ cfin){
  int b = blockIdx.x & 15, d = blockIdx.x >> 4;
  int j = threadIdx.x;                  // hc 0..255
  __shared__ float4 h4[64];
  if (j < 64) h4[j] = make_float4(0.f, 0.f, 0.f, 0.f);
  float c = 0.f;
  const ushort4* W = whh + (size_t)d * (256 * 256);
  const ushort4* xbase = xw + (size_t)d * 400 * 16 * 256;
  __syncthreads();
  for (int i = 0; i < 400; ++i){
    int s = d ? (399 - i) : i;
    ushort4 xv = xbase[((size_t)s * 16 + b) * 256 + j];
    float a0 = bf2f(xv.x), a1 = bf2f(xv.y), a2 = bf2f(xv.z), a3 = bf2f(xv.w);
#pragma unroll 4
    for (int kq = 0; kq < 64; ++kq){
      float4 hq = h4[kq];
      ushort4 w0 = W[(4*kq + 0) * 256 + j];
      ushort4 w1 = W[(4*kq + 1) * 256 + j];
      ushort4 w2 = W[(4*kq + 2) * 256 + j];
      ushort4 w3 = W[(4*kq + 3) * 256 + j];
      a0 += hq.x * bf2f(w0.x) + hq.y * bf2f(w1.x) + hq.z * bf2f(w2.x) + hq.w * bf2f(w3.x);
      a1 += hq.x * bf2f(w0.y) + hq.y * bf2f(w1.y) + hq.z * bf2f(w2.y) + hq.w * bf2f(w3.y);
      a2 += hq.x * bf2f(w0.z) + hq.y * bf2f(w1.z) + hq.z * bf2f(w2.z) + hq.w * bf2f(w3.z);
      a3 += hq.x * bf2f(w0.w) + hq.y * bf2f(w1.w) + hq.z * bf2f(w2.w) + hq.w * bf2f(w3.w);
    }
    float iv = sigm(a0), fv = sigm(a1), gv = tanh_f(a2), ov = sigm(a3);
    c = fv * c + iv * gv;
    float h = ov * tanh_f(c);
    __syncthreads();
    ((float*)h4)[j] = h;
    enc_out[((size_t)b * 400 + s) * 512 + d * 256 + j] = f2bf(h);
    __syncthreads();
  }
  hfin[(d * 16 + b) * 256 + j] = ((float*)h4)[j];
  cfin[(d * 16 + b) * 256 + j] = c;
}

__global__ void k_reduce(const float* __restrict__ hfin, const float* __restrict__ cfin,
                         const float* __restrict__ rhW, const float* __restrict__ rhb,
                         const float* __restrict__ rcW, const float* __restrict__ rcb,
                         float* __restrict__ h0, float* __restrict__ c0){
  int b = blockIdx.x, j = threadIdx.x;
  float ah = rhb[j], ac = rcb[j];
  for (int k = 0; k < 256; ++k){
    float hv = hfin[b * 256 + k], cv = cfin[b * 256 + k];
    ah += hv * rhW[k * 256 + j];
    ac += cv * rcW[k * 256 + j];
  }
  for (int k = 0; k < 256; ++k){
    float hv = hfin[(16 + b) * 256 + k], cv = cfin[(16 + b) * 256 + k];
    ah += hv * rhW[(256 + k) * 256 + j];
    ac += cv * rcW[(256 + k) * 256 + j];
  }
  h0[b * 256 + j] = tanh_f(ah);
  c0[b * 256 + j] = tanh_f(ac);
}

// enc_feat[b][s][j] = enc_out[b][s][:512] @ attn_Wh  (bf16 out)
__global__ void k_encfeat(const u16* __restrict__ enc_out, const float* __restrict__ Wh, u16* __restrict__ feat){
  int blk = blockIdx.x; int b = blk / 25; int sc = blk % 25;
  int j = threadIdx.x;
  float acc[16];
#pragma unroll
  for (int i = 0; i < 16; ++i) acc[i] = 0.f;
  const u32* ebase = (const u32*)(enc_out + ((size_t)b * 400 + sc * 16) * 512);
  for (int k2 = 0; k2 < 256; ++k2){
    float wa = Wh[(2 * k2) * 256 + j], wb_ = Wh[(2 * k2 + 1) * 256 + j];
#pragma unroll
    for (int ss = 0; ss < 16; ++ss){
      u32 p = ebase[ss * 256 + k2];
      acc[ss] += bf2f((u16)(p & 0xffff)) * wa + bf2f((u16)(p >> 16)) * wb_;
    }
  }
#pragma unroll
  for (int ss = 0; ss < 16; ++ss)
    feat[((size_t)b * 400 + sc * 16 + ss) * 256 + j] = f2bf(acc[ss]);
}

// ---------------- decoder precompute ----------------
__global__ void k_dec_pre(const int* __restrict__ din, const float* __restrict__ emb,
                          const float* __restrict__ Wih, const float* __restrict__ db,
                          const float* __restrict__ pgW,
                          float4* __restrict__ xwd, float* __restrict__ pg_emb){
  int blk = blockIdx.x; int t = blk / 16, b = blk % 16;
  int j = threadIdx.x;
  int id = din[b * 50 + t];
  const float* er = emb + (size_t)id * 128;
  float a0 = db[j], a1 = db[256 + j], a2 = db[512 + j], a3 = db[768 + j];
  for (int e = 0; e < 128; ++e){
    float x = er[e];
    const float* wr = Wih + (size_t)e * 1024;
    a0 += x * wr[j]; a1 += x * wr[256 + j]; a2 += x * wr[512 + j]; a3 += x * wr[768 + j];
  }
  xwd[(size_t)blk * 256 + j] = make_float4(a0, a1, a2, a3);
  __shared__ float red[256];
  float pe = 0.f;
  if (j < 128) pe = er[j] * pgW[768 + j];
  red[j] = pe; __syncthreads();
  for (int off = 128; off; off >>= 1){ if (j < off) red[j] += red[j + off]; __syncthreads(); }
  if (j == 0) pg_emb[blk] = red[0];
}

// ---------------- decoder step kernels ----------------
__global__ __launch_bounds__(256) void k_cell(const float* __restrict__ adec, const float* __restrict__ hin,
                                              const float* __restrict__ cin, const ushort4* __restrict__ Wp,
                                              const float4* __restrict__ xwd, int t,
                                              float* __restrict__ hout, float* __restrict__ cout,
                                              float* __restrict__ adec_h){
  int hcbase = blockIdx.x * 4;
  int tid = threadIdx.x;
  int b = tid & 15, hcl = (tid >> 4) & 3, ks = tid >> 6;
  __shared__ float a_lds[16][772];
  __shared__ float part[4][16][4][4];
  for (int idx = tid; idx < 16 * 512; idx += 256)
    a_lds[idx >> 9][idx & 511] = adec[(idx >> 9) * 768 + (idx & 511)];
  for (int idx = tid; idx < 16 * 256; idx += 256)
    a_lds[idx >> 8][512 + (idx & 255)] = hin[idx];
  __syncthreads();
  int hc = hcbase + hcl;
  float g0 = 0.f, g1 = 0.f, g2 = 0.f, g3 = 0.f;
  const ushort4* wb = Wp + hc;
  const float* arow = a_lds[b];
  for (int k = ks * 192; k < ks * 192 + 192; k += 4){
    float4 av = *(const float4*)(arow + k);
    ushort4 w0 = wb[(k + 0) * 256];
    ushort4 w1 = wb[(k + 1) * 256];
    ushort4 w2 = wb[(k + 2) * 256];
    ushort4 w3 = wb[(k + 3) * 256];
    g0 += av.x * bf2f(w0.x) + av.y * bf2f(w1.x) + av.z * bf2f(w2.x) + av.w * bf2f(w3.x);
    g1 += av.x * bf2f(w0.y) + av.y * bf2f(w1.y) + av.z * bf2f(w2.y) + av.w * bf2f(w3.y);
    g2 += av.x * bf2f(w0.z) + av.y * bf2f(w1.z) + av.z * bf2f(w2.z) + av.w * bf2f(w3.z);
    g3 += av.x * bf2f(w0.w) + av.y * bf2f(w1.w) + av.z * bf2f(w2.w) + av.w * bf2f(w3.w);
  }
  part[ks][b][hcl][0] = g0; part[ks][b][hcl][1] = g1;
  part[ks][b][hcl][2] = g2; part[ks][b][hcl][3] = g3;
  __syncthreads();
  if (tid < 64){
    int b2 = tid & 15, h2 = tid >> 4;
    float4 xv = xwd[((size_t)t * 16 + b2) * 256 + hcbase + h2];
    float s0 = xv.x + part[0][b2][h2][0] + part[1][b2][h2][0] + part[2][b2][h2][0] + part[3][b2][h2][0];
    float s1 = xv.y + part[0][b2][h2][1] + part[1][b2][h2][1] + part[2][b2][h2][1] + part[3][b2][h2][1];
    float s2 = xv.z + part[0][b2][h2][2] + part[1][b2][h2][2] + part[2][b2][h2][2] + part[3][b2][h2][2];
    float s3 = xv.w + part[0][b2][h2][3] + part[1][b2][h2][3] + part[2][b2][h2][3] + part[3][b2][h2][3];
    float iv = sigm(s0), fv = sigm(s1), gv = tanh_f(s2), ov = sigm(s3);
    int hcg = hcbase + h2;
    float cv = fv * cin[b2 * 256 + hcg] + iv * gv;
    float hv = ov * tanh_f(cv);
    cout[b2 * 256 + hcg] = cv;
    hout[b2 * 256 + hcg] = hv;
    adec_h[b2 * 768 + hcg] = hv;
  }
}

__global__ __launch_bounds__(256) void k_attn(const float* __restrict__ hnew, const u16* __restrict__ feat,
    const u16* __restrict__ enc_out, const int* __restrict__ src, const int* __restrict__ src_ext,
    const int* __restrict__ tgt_ext, const float* __restrict__ Ws, const float* __restrict__ Wsb,
    const float* __restrict__ Wc, const float* __restrict__ av_, const float* __restrict__ pgW,
    const float* __restrict__ pg_emb, const float* __restrict__ pgb, const float* __restrict__ pgbias,
    float* __restrict__ coverage, float* __restrict__ adec,
    float* __restrict__ pg_g, float* __restrict__ cvl_g, float* __restrict__ sct_g, int t){
  int b = blockIdx.x; int tid = threadIdx.x;
  __shared__ float hws_s[256];
  __shared__ float sc_s[400];
  __shared__ float at_s[400];
  __shared__ float ctx_s[512];
  __shared__ float red_s[4];
  // phase 1: h @ Ws + b
  {
    float acc = Wsb[tid];
    const float* hb_ = hnew + b * 256;
    for (int k = 0; k < 256; ++k) acc += hb_[k] * Ws[k * 256 + tid];
    hws_s[tid] = acc;
  }
  __syncthreads();
  // phase 2: scores
  {
    int w = tid >> 6, L = tid & 63;
    float4 hw = *(const float4*)&hws_s[4 * L];
    float4 wc = *(const float4*)&Wc[4 * L];
    float4 vv = *(const float4*)&av_[4 * L];
    for (int s = w; s < 400; s += 4){
      float cv = coverage[b * 400 + s];
      const u16* fp = feat + ((size_t)b * 400 + s) * 256 + 4 * L;
      u32 p0 = *(const u32*)fp; u32 p1 = *(const u32*)(fp + 2);
      float f0 = bf2f((u16)(p0 & 0xffff)) + hw.x + cv * wc.x;
      float f1 = bf2f((u16)(p0 >> 16))    + hw.y + cv * wc.y;
      float f2 = bf2f((u16)(p1 & 0xffff)) + hw.z + cv * wc.z;
      float f3 = bf2f((u16)(p1 >> 16))    + hw.w + cv * wc.w;
      float sc = tanh_f(f0) * vv.x + tanh_f(f1) * vv.y + tanh_f(f2) * vv.z + tanh_f(f3) * vv.w;
#pragma unroll
      for (int m = 32; m; m >>= 1) sc += __shfl_xor(sc, m);
      if (L == 0) sc_s[s] = (src[b * 400 + s] == 0) ? -1e9f : sc;
    }
  }
  __syncthreads();
  // phase 3: softmax over s
  {
    float m = -1e30f;
    for (int s = tid; s < 400; s += 256) m = fmaxf(m, sc_s[s]);
    float mx = blk_max(m, red_s);
    float e = 0.f;
    for (int s = tid; s < 400; s += 256){ float ee = __expf(sc_s[s] - mx); at_s[s] = ee; e += ee; }
    float sum = blk_sum(e, red_s);
    float inv = 1.f / sum;
    for (int s = tid; s < 400; s += 256) at_s[s] *= inv;
  }
  __syncthreads();
  // phase 4: context = attn @ enc_out
  {
    float a0 = 0.f, a1 = 0.f;
    const u16* eb = enc_out + (size_t)b * 400 * 512;
    for (int sq = 0; sq < 100; ++sq){
      float4 aq = *(const float4*)&at_s[4 * sq];
      const u16* r0 = eb + (size_t)(4 * sq) * 512;
      a0 += aq.x * bf2f(r0[tid])        + aq.y * bf2f(r0[512 + tid])
          + aq.z * bf2f(r0[1024 + tid]) + aq.w * bf2f(r0[1536 + tid]);
      a1 += aq.x * bf2f(r0[256 + tid])  + aq.y * bf2f(r0[768 + tid])
          + aq.z * bf2f(r0[1280 + tid]) + aq.w * bf2f(r0[1792 + tid]);
    }
    ctx_s[tid] = a0; ctx_s[256 + tid] = a1;
    adec[b * 768 + tid] = a0; adec[b * 768 + 256 + tid] = a1;
  }
  // phase 5: coverage loss / update / scatter-sum (reads old coverage; phase-2 reads are done)
  float clp = 0.f, scp = 0.f;
  {
    int tg = tgt_ext[b * 50 + t];
    for (int s = tid; s < 400; s += 256){
      float a = at_s[s];
      float cv = coverage[b * 400 + s];
      clp += fminf(a, cv);
      coverage[b * 400 + s] = cv + a;
      if (src_ext[b * 400 + s] == tg) scp += a;
    }
  }
  __syncthreads();
  // phase 6: pgen
  {
    float p = ctx_s[tid] * pgW[tid] + ctx_s[256 + tid] * pgW[256 + tid] + hnew[b * 256 + tid] * pgW[512 + tid];
    float dsum = blk_sum(p, red_s);
    float cl = blk_sum(clp, red_s);
    float sc2 = blk_sum(scp, red_s);
    if (tid == 0){
      float pg = sigm(dsum + pg_emb[t * 16 + b] + pgb[0] + pgbias[0]);
      pg = fminf(fmaxf(pg, 0.1f), 0.9f);
      pg_g[b] = pg; cvl_g[b] = cl; sct_g[b] = sc2;
    }
  }
}

__global__ __launch_bounds__(256) void k_vocab(const float* __restrict__ adec, const float* __restrict__ vW,
    const float* __restrict__ vb, const int* __restrict__ tgt_ext, int t,
    float* __restrict__ mpart, float* __restrict__ spart, float* __restrict__ ltgt){
  int col0 = blockIdx.x * 128;
  int tid = threadIdx.x;
  int cl = tid & 127, half = tid >> 7;
  int col = col0 + cl;
  float acc[16];
#pragma unroll
  for (int i = 0; i < 16; ++i) acc[i] = 0.f;
  const float* Wc = vW + col;
  for (int k = half * 384; k < half * 384 + 384; k += 4){
    float w0 = Wc[(size_t)(k + 0) * 32000];
    float w1 = Wc[(size_t)(k + 1) * 32000];
    float w2 = Wc[(size_t)(k + 2) * 32000];
    float w3 = Wc[(size_t)(k + 3) * 32000];
#pragma unroll
    for (int b = 0; b < 16; ++b){
      const float* Ab = adec + b * 768 + k;
      acc[b] += Ab[0] * w0 + Ab[1] * w1 + Ab[2] * w2 + Ab[3] * w3;
    }
  }
  __shared__ float Ls[2][16][128];
#pragma unroll
  for (int b2 = 0; b2 < 16; ++b2) Ls[half][b2][cl] = acc[b2];
  __syncthreads();
  if (half == 0){
    float vbc = vb[col];
#pragma unroll
    for (int b2 = 0; b2 < 16; ++b2) Ls[0][b2][cl] = Ls[0][b2][cl] + Ls[1][b2][cl] + vbc;
  }
  __syncthreads();
  {
    int b2 = tid >> 4, l16 = tid & 15;
    float m = -1e30f, ssum = 0.f;
#pragma unroll
    for (int i = 0; i < 8; ++i){
      float x = Ls[0][b2][l16 + 16 * i];
      float M = fmaxf(m, x);
      ssum = ssum * __expf(m - M) + __expf(x - M);
      m = M;
    }
#pragma unroll
    for (int mk = 1; mk < 16; mk <<= 1){
      float om = __shfl_xor(m, mk), os = __shfl_xor(ssum, mk);
      float M = fmaxf(m, om);
      ssum = ssum * __expf(m - M) + os * __expf(om - M);
      m = M;
    }
    if (l16 == 0){ mpart[b2 * 250 + blockIdx.x] = m; spart[b2 * 250 + blockIdx.x] = ssum; }
  }
  if (tid < 16){
    int tg = tgt_ext[tid * 50 + t];
    unsigned offc = (unsigned)(tg - col0);
    if (offc < 128u) ltgt[tid] = Ls[0][tid][offc];
  }
}

__global__ void k_comb(const float* __restrict__ mpart, const float* __restrict__ spart,
                       const float* __restrict__ ltgt, const float* __restrict__ pg_g,
                       const float* __restrict__ cvl_g, const float* __restrict__ sct_g,
                       const int* __restrict__ tgt_ext, const float* __restrict__ lam, int t,
                       float* __restrict__ loss_g, float* __restrict__ valid_g){
  int tid = threadIdx.x;
  int b = tid >> 4, l16 = tid & 15;
  float m = -1e30f, s = 0.f;
  for (int i = l16; i < 250; i += 16){
    float om = mpart[b * 250 + i], os = spart[b * 250 + i];
    float M = fmaxf(m, om);
    s = s * __expf(m - M) + os * __expf(om - M);
    m = M;
  }
#pragma unroll
  for (int mk = 1; mk < 16; mk <<= 1){
    float om = __shfl_xor(m, mk), os = __shfl_xor(s, mk);
    float M = fmaxf(m, om);
    s = s * __expf(m - M) + os * __expf(om - M);
    m = M;
  }
  if (l16 == 0){
    int tg = tgt_ext[b * 50 + t];
    float pv = (tg < 32000) ? (__expf(ltgt[b] - m) / s) : 0.f;
    float pg = pg_g[b];
    float pf = pg * pv + (1.f - pg) * sct_g[b];
    float sl = -__logf(pf + 1e-12f);
    float msk = (tg != 0) ? 1.f : 0.f;
    loss_g[t * 16 + b] = (sl + lam[0] * cvl_g[b]) * msk;
    valid_g[t * 16 + b] = msk;
  }
}

__global__ void k_final(const float* __restrict__ loss_g, const float* __restrict__ valid_g, float* __restrict__ out){
  __shared__ float r1[256], r2[256];
  int tid = threadIdx.x;
  float a = 0.f, v = 0.f;
  for (int i = tid; i < 800; i += 256){ a += loss_g[i]; v += valid_g[i]; }
  r1[tid] = a; r2[tid] = v; __syncthreads();
  for (int off = 128; off; off >>= 1){
    if (tid < off){ r1[tid] += r1[tid + off]; r2[tid] += r2[tid + off]; }
    __syncthreads();
  }
  if (tid == 0) out[0] = r1[0] / fmaxf(r2[0], 1.f);
}

extern "C" void kernel_launch(void* const* d_in, const int* in_sizes, int n_in,
                              void* d_out, int out_size, void* d_ws, size_t ws_size,
                              hipStream_t stream){
  const int*   src     = (const int*)  d_in[0];
  const int*   src_ext = (const int*)  d_in[1];
  const int*   dec_in  = (const int*)  d_in[2];
  const int*   tgt_ext = (const int*)  d_in[3];
  const float* enc_emb = (const float*)d_in[5];
  const float* eWihF   = (const float*)d_in[6];
  const float* eWhhF   = (const float*)d_in[7];
  const float* ebF     = (const float*)d_in[8];
  const float* eWihB   = (const float*)d_in[9];
  const float* eWhhB   = (const float*)d_in[10];
  const float* ebB     = (const float*)d_in[11];
  const float* rhW     = (const float*)d_in[12];
  const float* rhb     = (const float*)d_in[13];
  const float* rcW     = (const float*)d_in[14];
  const float* rcb     = (const float*)d_in[15];
  const float* dec_emb = (const float*)d_in[16];
  const float* dWih    = (const float*)d_in[17];
  const float* dWhh    = (const float*)d_in[18];
  const float* db_     = (const float*)d_in[19];
  const float* aWh     = (const float*)d_in[20];
  const float* aWs     = (const float*)d_in[21];
  const float* aWsb    = (const float*)d_in[22];
  const float* aWc     = (const float*)d_in[23];
  const float* av      = (const float*)d_in[24];
  const float* pgW     = (const float*)d_in[25];
  const float* pgb     = (const float*)d_in[26];
  const float* vW      = (const float*)d_in[27];
  const float* vb      = (const float*)d_in[28];
  const float* lam     = (const float*)d_in[29];
  const float* pgbias  = (const float*)d_in[30];
  (void)in_sizes; (void)n_in; (void)out_size; (void)ws_size;

  char* w = (char*)d_ws;
  size_t off = 0;
  auto alloc = [&](size_t bytes) -> char* {
    char* p = w + off; off += (bytes + 255) & ~(size_t)255; return p;
  };
  ushort4* xw     = (ushort4*)alloc(2ull * 400 * 16 * 256 * 8);   // 26.2 MB
  ushort4* whhp   = (ushort4*)alloc(2ull * 256 * 256 * 8);        // 1.05 MB
  ushort4* decwp  = (ushort4*)alloc(768ull * 256 * 8);            // 1.57 MB
  u16*     enc_out= (u16*)    alloc(16ull * 400 * 512 * 2);       // 6.55 MB
  u16*     feat   = (u16*)    alloc(16ull * 400 * 256 * 2);       // 3.28 MB
  float*   hfin   = (float*)  alloc(2 * 16 * 256 * 4);
  float*   cfin   = (float*)  alloc(2 * 16 * 256 * 4);
  float*   hbuf   = (float*)  alloc(2 * 16 * 256 * 4);
  float*   cbuf   = (float*)  alloc(2 * 16 * 256 * 4);
  float4*  xwd    = (float4*) alloc(50ull * 16 * 256 * 16);       // 3.28 MB
  float*   pg_emb = (float*)  alloc(800 * 4);
  float*   coverage=(float*)  alloc(16 * 400 * 4);                // 25600 (256-aligned)
  float*   adec   = (float*)  alloc(16 * 768 * 4);                // 49152, adjacent to coverage
  float*   mpart  = (float*)  alloc(16 * 250 * 4);
  float*   spart  = (float*)  alloc(16 * 250 * 4);
  float*   ltgt   = (float*)  alloc(64);
  float*   pg_g   = (float*)  alloc(64);
  float*   cvl_g  = (float*)  alloc(64);
  float*   sct_g  = (float*)  alloc(64);
  float*   loss_g = (float*)  alloc(800 * 4);
  float*   valid_g= (float*)  alloc(800 * 4);

  // zero coverage + adec (contiguous)
  hipMemsetAsync(coverage, 0, 16 * 400 * 4 + 16 * 768 * 4, stream);

  hipLaunchKernelGGL(k_pack_whh,  dim3(512),   dim3(256), 0, stream, eWhhF, eWhhB, whhp);
  hipLaunchKernelGGL(k_pack_decw, dim3(768),   dim3(256), 0, stream, dWih, dWhh, decwp);
  hipLaunchKernelGGL(k_enc_pre,   dim3(12800), dim3(256), 0, stream, src, enc_emb, eWihF, ebF, eWihB, ebB, xw);
  hipLaunchKernelGGL(k_dec_pre,   dim3(800),   dim3(256), 0, stream, dec_in, dec_emb, dWih, db_, pgW, xwd, pg_emb);
  hipLaunchKernelGGL(k_enc_lstm,  dim3(32),    dim3(256), 0, stream, xw, whhp, enc_out, hfin, cfin);
  hipLaunchKernelGGL(k_reduce,    dim3(16),    dim3(256), 0, stream, hfin, cfin, rhW, rhb, rcW, rcb, hbuf, cbuf);
  hipLaunchKernelGGL(k_encfeat,   dim3(400),   dim3(256), 0, stream, enc_out, aWh, feat);

  for (int t = 0; t < 50; ++t){
    float* hin  = hbuf + (t & 1) * 16 * 256;
    float* hout = hbuf + ((t + 1) & 1) * 16 * 256;
    float* cin  = cbuf + (t & 1) * 16 * 256;
    float* cout = cbuf + ((t + 1) & 1) * 16 * 256;
    hipLaunchKernelGGL(k_cell,  dim3(64),  dim3(256), 0, stream, adec, hin, cin, decwp, xwd, t, hout, cout, adec + 512);
    hipLaunchKernelGGL(k_attn,  dim3(16),  dim3(256), 0, stream, hout, feat, enc_out, src, src_ext, tgt_ext,
                       aWs, aWsb, aWc, av, pgW, pg_emb, pgb, pgbias, coverage, adec, pg_g, cvl_g, sct_g, t);
    hipLaunchKernelGGL(k_vocab, dim3(250), dim3(256), 0, stream, adec, vW, vb, tgt_ext, t, mpart, spart, ltgt);
    hipLaunchKernelGGL(k_comb,  dim3(1),   dim3(256), 0, stream, mpart, spart, ltgt, pg_g, cvl_g, sct_g, tgt_ext, lam, t, loss_g, valid_g);
  }
  hipLaunchKernelGGL(k_final, dim3(1), dim3(256), 0, stream, loss_g, valid_g, (float*)d_out);
}